// Round 4
// baseline (225.391 us; speedup 1.0000x reference)
//
#include <hip/hip_runtime.h>

typedef short bf16x8 __attribute__((ext_vector_type(8)));
typedef float f32x4 __attribute__((ext_vector_type(4)));
typedef unsigned long long u64;

#define N_NODES 4096
#define N_EDGES 16384
#define FN 128
#define FE 64
#define NJS 8
#define EJS 16
#define WPR 64   // packed u64 words per row (4096 bits)

__device__ __forceinline__ float lrelu(float x) { return x >= 0.f ? x : 0.01f * x; }
// float -> bf16 round-to-nearest-even (finite inputs only)
__device__ __forceinline__ unsigned short f2bf(float f) {
    unsigned int x = __float_as_uint(f);
    return (unsigned short)((x + 0x7fffu + ((x >> 16) & 1u)) >> 16);
}

// ---- kernel 0: bit-pack masks, row-major fully-coalesced streaming ----
// Bit layout per row: for column i, word = (i>>8)*4 + (i&3), bit = (i>>2)&63.
__global__ __launch_bounds__(256) void k_pack(
    const int* __restrict__ adj, const int* __restrict__ eadj,
    u64* __restrict__ adjP, u64* __restrict__ eadjP) {
    const int wv = threadIdx.x >> 6, ln = threadIdx.x & 63;
    const int row = blockIdx.x * 4 + wv;   // 0..20479
    const int* src;
    u64* dst;
    if (row < N_EDGES) {
        src = eadj + (size_t)row * N_NODES;
        dst = eadjP + (size_t)row * WPR;
    } else {
        src = adj + (size_t)(row - N_EDGES) * N_NODES;
        dst = adjP + (size_t)(row - N_EDGES) * WPR;
    }
#pragma unroll 4
    for (int chunk = 0; chunk < 16; ++chunk) {
        int4 v = *(const int4*)(src + chunk * 256 + ln * 4);
        u64 b0 = __ballot(v.x > 0);
        u64 b1 = __ballot(v.y > 0);
        u64 b2 = __ballot(v.z > 0);
        u64 b3 = __ballot(v.w > 0);
        if (ln < 4) dst[chunk * 4 + ln] = (ln == 0) ? b0 : (ln == 1) ? b1 : (ln == 2) ? b2 : b3;
    }
}

// ---- kernel 1: per-node h = nf@Wn row, then alpha/beta/gamma dots ----
__global__ __launch_bounds__(256) void k_node_proj(
    const float* __restrict__ nf, const float* __restrict__ Wn,
    const float* __restrict__ pvn, const float* __restrict__ pve,
    float* __restrict__ alpha, float* __restrict__ beta, float* __restrict__ gamma) {
    __shared__ float row[4][FN];
    const int wv = threadIdx.x >> 6, ln = threadIdx.x & 63;
    const int i = blockIdx.x * 4 + wv;
    float2 r2 = *(const float2*)(nf + (size_t)i * FN + ln * 2);
    row[wv][ln * 2] = r2.x; row[wv][ln * 2 + 1] = r2.y;
    __syncthreads();
    float h0 = 0.f, h1 = 0.f;
#pragma unroll 8
    for (int k = 0; k < FN; ++k) {
        float nv = row[wv][k];
        float2 w2 = *(const float2*)(Wn + (size_t)k * FN + ln * 2);
        h0 = fmaf(nv, w2.x, h0); h1 = fmaf(nv, w2.y, h1);
    }
    float2 as = *(const float2*)(pvn + ln * 2);
    float2 an = *(const float2*)(pvn + FN + ln * 2);
    float2 bs = *(const float2*)(pve + ln * 2);
    float pa = h0 * as.x + h1 * as.y;
    float pb = h0 * an.x + h1 * an.y;
    float pg = h0 * bs.x + h1 * bs.y;
#pragma unroll
    for (int off = 32; off > 0; off >>= 1) {
        pa += __shfl_down(pa, off, 64);
        pb += __shfl_down(pb, off, 64);
        pg += __shfl_down(pg, off, 64);
    }
    if (ln == 0) { alpha[i] = pa; beta[i] = pb; gamma[i] = pg; }
}

// ---- kernel 2: per-edge he = ef@We row, then betaE = he@b_edge ----
__global__ __launch_bounds__(256) void k_edge_proj(
    const float* __restrict__ ef, const float* __restrict__ We,
    const float* __restrict__ pve, float* __restrict__ betaE) {
    __shared__ float row[4][FE];
    const int wv = threadIdx.x >> 6, ln = threadIdx.x & 63;
    const int e = blockIdx.x * 4 + wv;
    row[wv][ln] = ef[(size_t)e * FE + ln];
    __syncthreads();
    float h = 0.f;
#pragma unroll 8
    for (int k = 0; k < FE; ++k)
        h = fmaf(row[wv][k], We[(size_t)k * FE + ln], h);
    float p = h * pve[FN + ln];
#pragma unroll
    for (int off = 32; off > 0; off >>= 1) p += __shfl_down(p, off, 64);
    if (ln == 0) betaE[e] = p;
}

// ---- kernel 3: global maxes of beta (block 0) and betaE (block 1) ----
__global__ __launch_bounds__(256) void k_maxes(
    const float* __restrict__ beta, const float* __restrict__ betaE,
    float* __restrict__ maxes) {
    const float* src = blockIdx.x == 0 ? beta : betaE;
    const int n = blockIdx.x == 0 ? N_NODES : N_EDGES;
    float m = -3.0e38f;
    for (int t = threadIdx.x; t < n; t += 256) m = fmaxf(m, src[t]);
#pragma unroll
    for (int off = 32; off > 0; off >>= 1) m = fmaxf(m, __shfl_down(m, off, 64));
    __shared__ float sm[4];
    if ((threadIdx.x & 63) == 0) sm[threadIdx.x >> 6] = m;
    __syncthreads();
    if (threadIdx.x == 0)
        maxes[blockIdx.x] = fmaxf(fmaxf(sm[0], sm[1]), fmaxf(sm[2], sm[3]));
}

// ---- kernel 4: transpose + bf16 convert: src[J][F] f32 -> dst[F][J] bf16 ----
__global__ __launch_bounds__(256) void k_prep(
    const float* __restrict__ src, unsigned short* __restrict__ dst,
    const int J, const int F) {
    __shared__ float tile[64][65];
    const int t = threadIdx.x;
    const int j0 = blockIdx.x * 64, f0 = blockIdx.y * 64;
#pragma unroll
    for (int p = 0; p < 4; ++p) {
        int j = (t >> 4) + p * 16;
        float4 v = *(const float4*)(src + (size_t)(j0 + j) * F + f0 + (t & 15) * 4);
        tile[j][(t & 15) * 4 + 0] = v.x;
        tile[j][(t & 15) * 4 + 1] = v.y;
        tile[j][(t & 15) * 4 + 2] = v.z;
        tile[j][(t & 15) * 4 + 3] = v.w;
    }
    __syncthreads();
#pragma unroll
    for (int p = 0; p < 2; ++p) {
        int f = (t >> 3) + p * 32;
        int c = t & 7;
        bf16x8 v;
#pragma unroll
        for (int e = 0; e < 8; ++e) v[e] = (short)f2bf(tile[c * 8 + e][f]);
        *(bf16x8*)(dst + (size_t)(f0 + f) * J + j0 + c * 8) = v;
    }
}

// ---- kernel 5: node attention aggregation, MFMA, packed masks ----
__global__ __launch_bounds__(256) void k_node_att(
    const unsigned short* __restrict__ Xt,   // [128][4096] bf16
    const u64* __restrict__ adjP,
    const float* __restrict__ alpha, const float* __restrict__ beta,
    const float* __restrict__ maxes,
    float* __restrict__ accP, float* __restrict__ zP, float* __restrict__ degP) {
    __shared__ unsigned short xlds[2][128 * 64];  // 32 KB, XOR-swizzled chunks
    __shared__ unsigned short wlds[2][4 * 512];   // 8 KB  [kb*2+nb][lane*8]
    __shared__ float bb[512];
    __shared__ float zred[8][32];
    __shared__ float dred[8][32];
    const int t = threadIdx.x;
    const int i0 = blockIdx.x * 32;
    const int bj = blockIdx.y;
    const int j0 = bj * (N_NODES / NJS);       // 512 j per block
    const int il = t & 31;
    const int jg = t >> 5;                     // 0..7
    const float a_i = alpha[i0 + il];
    const float m_i = lrelu(a_i + maxes[0]);
    if (t < 128) *(float4*)&bb[t * 4] = *(const float4*)(beta + j0 + t * 4);
    const int l = t & 63, wid = t >> 6;
    const int wm = wid >> 1, wn = wid & 1;
    const int l15 = l & 15, l4 = l >> 4;
    const int sf = t >> 3, sc = t & 7;         // stage: rows sf+32p, chunk sc
    const int xswz = (sc ^ (sf & 7)) * 8;
    const int wdst = ((jg >> 2) * 2 + (il >> 4)) * 512 + ((il & 15) + 16 * (jg & 3)) * 8;
    f32x4 acc[4] = {{0,0,0,0},{0,0,0,0},{0,0,0,0},{0,0,0,0}};
    float zacc = 0.f, dacc = 0.f;

    // packed-mask addressing: word = (i>>8)*4 + (i&3), bit = (i>>2)&63
    const u64* mp0 = adjP + (size_t)(j0 + jg * 8) * WPR + ((i0 >> 8) * 4 + (il & 3));
    const int mbit = ((i0 + il) >> 2) & 63;
    const unsigned short* xs0 = Xt + (size_t)sf * N_NODES + j0 + sc * 8;

    // prologue: loads for ks=0
    int mk[8];
#pragma unroll
    for (int e = 0; e < 8; ++e) mk[e] = (int)((mp0[(size_t)e * WPR] >> mbit) & 1);
    bf16x8 xv0 = *(const bf16x8*)(xs0);
    bf16x8 xv1 = *(const bf16x8*)(xs0 + (size_t)32 * N_NODES);
    bf16x8 xv2 = *(const bf16x8*)(xs0 + (size_t)64 * N_NODES);
    bf16x8 xv3 = *(const bf16x8*)(xs0 + (size_t)96 * N_NODES);
    __syncthreads();   // bb visible

    int buf = 0;
    for (int ks = 0; ks < 8; ++ks) {
        const int jb = ks * 64;
        // w-gen from prefetched regs
        bf16x8 wfrag;
#pragma unroll
        for (int e = 0; e < 8; ++e) {
            float s = lrelu(a_i + bb[jb + jg * 8 + e]);
            float w = mk[e] ? __expf(s - m_i) : 0.f;
            zacc += w;
            dacc += (float)mk[e];
            wfrag[e] = (short)f2bf(w);
        }
        // stage LDS
        *(bf16x8*)&xlds[buf][(sf +  0) * 64 + xswz] = xv0;
        *(bf16x8*)&xlds[buf][(sf + 32) * 64 + xswz] = xv1;
        *(bf16x8*)&xlds[buf][(sf + 64) * 64 + xswz] = xv2;
        *(bf16x8*)&xlds[buf][(sf + 96) * 64 + xswz] = xv3;
        *(bf16x8*)&wlds[buf][wdst] = wfrag;
        // prefetch next iteration
        if (ks + 1 < 8) {
            const int jbn = jb + 64;
            const u64* mp = mp0 + (size_t)jbn * WPR;
#pragma unroll
            for (int e = 0; e < 8; ++e) mk[e] = (int)((mp[(size_t)e * WPR] >> mbit) & 1);
            const unsigned short* xs = xs0 + jbn;
            xv0 = *(const bf16x8*)(xs);
            xv1 = *(const bf16x8*)(xs + (size_t)32 * N_NODES);
            xv2 = *(const bf16x8*)(xs + (size_t)64 * N_NODES);
            xv3 = *(const bf16x8*)(xs + (size_t)96 * N_NODES);
        }
        __syncthreads();   // publish buf
#pragma unroll
        for (int kb = 0; kb < 2; ++kb) {
            bf16x8 b = *(const bf16x8*)&wlds[buf][(kb * 2 + wn) * 512 + l * 8];
#pragma unroll
            for (int mi = 0; mi < 4; ++mi) {
                const int fr = wm * 64 + mi * 16 + l15;
                bf16x8 a = *(const bf16x8*)&xlds[buf][fr * 64 + (((kb * 4 + l4) ^ (fr & 7)) * 8)];
                acc[mi] = __builtin_amdgcn_mfma_f32_16x16x32_bf16(a, b, acc[mi], 0, 0, 0);
            }
        }
        buf ^= 1;
    }
    zred[jg][il] = zacc;
    dred[jg][il] = dacc;
    __syncthreads();
    if (t < 32) {
        float z = 0.f, d = 0.f;
#pragma unroll
        for (int g = 0; g < 8; ++g) { z += zred[g][t]; d += dred[g][t]; }
        zP[bj * N_NODES + i0 + t] = z;
        degP[bj * N_NODES + i0 + t] = d;
    }
    const int ig = i0 + wn * 16 + l15;
#pragma unroll
    for (int mi = 0; mi < 4; ++mi) {
        const int fg = wm * 64 + mi * 16 + l4 * 4;
        *(f32x4*)(accP + ((size_t)bj * N_NODES + ig) * FN + fg) = acc[mi];
    }
}

// ---- kernel 6: edge attention aggregation, MFMA, KSTEP=64, packed masks ----
__global__ __launch_bounds__(256) void k_edge_att(
    const unsigned short* __restrict__ Xt,   // [64][16384] bf16
    const u64* __restrict__ eadjP,
    const float* __restrict__ gamma, const float* __restrict__ betaE,
    const float* __restrict__ maxes,
    float* __restrict__ accP, float* __restrict__ zP, float* __restrict__ degP) {
    __shared__ unsigned short xlds[2][64 * 64];   // 16 KB, swizzled chunks
    __shared__ unsigned short wlds[2][8 * 512];   // 16 KB [kb*4+nb][lane*8]
    __shared__ float bb[1024];
    __shared__ float zred[4][64];
    __shared__ float dred[4][64];
    const int t = threadIdx.x;
    const int i0 = blockIdx.x * 64;
    const int bj = blockIdx.y;
    const int j0 = bj * (N_EDGES / EJS);       // 1024 j per block
    const int il = t & 63;
    const int jg = t >> 6;                     // 0..3 (wave id)
    const float g_i = gamma[i0 + il];
    const float m_i = lrelu(g_i + maxes[1]);
    *(float4*)&bb[t * 4] = *(const float4*)(betaE + j0 + t * 4);
    const int l = t & 63, wid = t >> 6;
    const int wm = wid >> 1, wn = wid & 1;
    const int l15 = l & 15, l4 = l >> 4;
    const int sf = t >> 2, sc = t & 3;         // stage: row sf, chunks sc / sc+4
    const int xd0 = sf * 64 + ((sc       ^ (sf & 7)) * 8);
    const int xd1 = sf * 64 + (((sc + 4) ^ (sf & 7)) * 8);
    const unsigned short* xsrc = Xt + (size_t)sf * N_EDGES + j0 + sc * 8;
    const int wl = (il & 15) + 16 * jg;        // lane-in-frag
    const int nb = il >> 4;
    f32x4 acc[2][2] = {{{0,0,0,0},{0,0,0,0}},{{0,0,0,0},{0,0,0,0}}};
    float zacc = 0.f, dacc = 0.f;

    // packed-mask addressing
    const u64* mp0 = eadjP + (size_t)(j0 + jg * 8) * WPR + ((i0 >> 8) * 4 + (il & 3));
    const int mbit = ((i0 + il) >> 2) & 63;

    // prologue loads (ks=0)
    int mk0[8], mk1[8];
#pragma unroll
    for (int e = 0; e < 8; ++e) mk0[e] = (int)((mp0[(size_t)e * WPR] >> mbit) & 1);
#pragma unroll
    for (int e = 0; e < 8; ++e) mk1[e] = (int)((mp0[(size_t)(32 + e) * WPR] >> mbit) & 1);
    bf16x8 xv0 = *(const bf16x8*)(xsrc);
    bf16x8 xv1 = *(const bf16x8*)(xsrc + 32);
    __syncthreads();   // bb visible

    int buf = 0;
    for (int ks = 0; ks < 16; ++ks) {
        const int jb = ks * 64;
        // w-gen from prefetched regs
        bf16x8 wf0, wf1;
#pragma unroll
        for (int e = 0; e < 8; ++e) {
            float s0 = lrelu(g_i + bb[jb + jg * 8 + e]);
            float w0 = mk0[e] ? __expf(s0 - m_i) : 0.f;
            float s1 = lrelu(g_i + bb[jb + 32 + jg * 8 + e]);
            float w1 = mk1[e] ? __expf(s1 - m_i) : 0.f;
            zacc += w0 + w1;
            dacc += (float)(mk0[e] + mk1[e]);
            wf0[e] = (short)f2bf(w0);
            wf1[e] = (short)f2bf(w1);
        }
        // stage LDS
        *(bf16x8*)&xlds[buf][xd0] = xv0;
        *(bf16x8*)&xlds[buf][xd1] = xv1;
        *(bf16x8*)&wlds[buf][(0 * 4 + nb) * 512 + wl * 8] = wf0;
        *(bf16x8*)&wlds[buf][(1 * 4 + nb) * 512 + wl * 8] = wf1;
        // prefetch next iteration
        if (ks + 1 < 16) {
            const int jbn = jb + 64;
            const u64* mp = mp0 + (size_t)jbn * WPR;
#pragma unroll
            for (int e = 0; e < 8; ++e) mk0[e] = (int)((mp[(size_t)e * WPR] >> mbit) & 1);
#pragma unroll
            for (int e = 0; e < 8; ++e) mk1[e] = (int)((mp[(size_t)(32 + e) * WPR] >> mbit) & 1);
            xv0 = *(const bf16x8*)(xsrc + jbn);
            xv1 = *(const bf16x8*)(xsrc + jbn + 32);
        }
        __syncthreads();   // publish buf
#pragma unroll
        for (int kb = 0; kb < 2; ++kb) {
            bf16x8 b0 = *(const bf16x8*)&wlds[buf][(kb * 4 + wn * 2 + 0) * 512 + l * 8];
            bf16x8 b1 = *(const bf16x8*)&wlds[buf][(kb * 4 + wn * 2 + 1) * 512 + l * 8];
#pragma unroll
            for (int mi = 0; mi < 2; ++mi) {
                const int fr = wm * 32 + mi * 16 + l15;
                bf16x8 a = *(const bf16x8*)&xlds[buf][fr * 64 + (((kb * 4 + l4) ^ (fr & 7)) * 8)];
                acc[mi][0] = __builtin_amdgcn_mfma_f32_16x16x32_bf16(a, b0, acc[mi][0], 0, 0, 0);
                acc[mi][1] = __builtin_amdgcn_mfma_f32_16x16x32_bf16(a, b1, acc[mi][1], 0, 0, 0);
            }
        }
        buf ^= 1;
    }
    zred[jg][il] = zacc;
    dred[jg][il] = dacc;
    __syncthreads();
    if (t < 64) {
        float z = zred[0][t] + zred[1][t] + zred[2][t] + zred[3][t];
        float d = dred[0][t] + dred[1][t] + dred[2][t] + dred[3][t];
        zP[bj * N_NODES + i0 + t] = z;
        degP[bj * N_NODES + i0 + t] = d;
    }
    const size_t obase = (size_t)bj * N_NODES;
#pragma unroll
    for (int mi = 0; mi < 2; ++mi) {
#pragma unroll
        for (int p = 0; p < 2; ++p) {
            int ig = i0 + wn * 32 + p * 16 + l15;
            int fg = wm * 32 + mi * 16 + l4 * 4;
            *(f32x4*)(accP + (obase + ig) * FE + fg) = acc[mi][p];
        }
    }
}

// ---- kernel 7: node epilogue ----
__global__ __launch_bounds__(256) void k_node_out(
    const float* __restrict__ accP, const float* __restrict__ zP,
    const float* __restrict__ degP, const float* __restrict__ Wn,
    float* __restrict__ out) {
    __shared__ float ml[4][FN];
    const int wv = threadIdx.x >> 6, ln = threadIdx.x & 63;
    const int i = blockIdx.x * 4 + wv;
    float s0 = 0.f, s1 = 0.f;
#pragma unroll
    for (int js = 0; js < NJS; ++js) {
        float2 v = *(const float2*)(accP + ((size_t)js * N_NODES + i) * FN + ln * 2);
        s0 += v.x; s1 += v.y;
    }
    float z = 0.f, d = 0.f;
#pragma unroll
    for (int js = 0; js < NJS; ++js) { z += zP[js * N_NODES + i]; d += degP[js * N_NODES + i]; }
    float zd = z * d;
    float inv = zd > 0.f ? 1.f / zd : 0.f;
    ml[wv][ln * 2] = s0 * inv; ml[wv][ln * 2 + 1] = s1 * inv;
    __syncthreads();
    float o0 = 0.f, o1 = 0.f;
#pragma unroll 8
    for (int k = 0; k < FN; ++k) {
        float mvv = ml[wv][k];
        float2 w2 = *(const float2*)(Wn + (size_t)k * FN + ln * 2);
        o0 = fmaf(mvv, w2.x, o0); o1 = fmaf(mvv, w2.y, o1);
    }
    out[(size_t)i * 192 + ln * 2] = lrelu(o0);
    out[(size_t)i * 192 + ln * 2 + 1] = lrelu(o1);
}

// ---- kernel 8: edge epilogue ----
__global__ __launch_bounds__(256) void k_edge_out(
    const float* __restrict__ accP, const float* __restrict__ zP,
    const float* __restrict__ degP, const float* __restrict__ We,
    float* __restrict__ out) {
    __shared__ float ml[4][FE];
    const int wv = threadIdx.x >> 6, ln = threadIdx.x & 63;
    const int i = blockIdx.x * 4 + wv;
    float s = 0.f;
#pragma unroll
    for (int js = 0; js < EJS; ++js)
        s += accP[((size_t)js * N_NODES + i) * FE + ln];
    float z = 0.f, d = 0.f;
#pragma unroll
    for (int js = 0; js < EJS; ++js) { z += zP[js * N_NODES + i]; d += degP[js * N_NODES + i]; }
    float zd = z * d;
    float inv = zd > 0.f ? 1.f / zd : 0.f;
    ml[wv][ln] = s * inv;
    __syncthreads();
    float o = 0.f;
#pragma unroll 8
    for (int k = 0; k < FE; ++k)
        o = fmaf(ml[wv][k], We[(size_t)k * FE + ln], o);
    out[(size_t)i * 192 + 128 + ln] = lrelu(o);
}

extern "C" void kernel_launch(void* const* d_in, const int* in_sizes, int n_in,
                              void* d_out, int out_size, void* d_ws, size_t ws_size,
                              hipStream_t stream) {
    (void)in_sizes; (void)n_in; (void)out_size; (void)ws_size;
    const float* nf   = (const float*)d_in[0];
    const float* ef   = (const float*)d_in[1];
    const int*   adj  = (const int*)d_in[2];
    const int*   eadj = (const int*)d_in[3];
    const float* Wn   = (const float*)d_in[4];
    const float* We   = (const float*)d_in[5];
    const float* pvn  = (const float*)d_in[6];
    const float* pve  = (const float*)d_in[7];
    float* out = (float*)d_out;

    u64* adjP  = (u64*)d_ws;                            // 4096*64 u64 = 2 MB
    u64* eadjP = adjP + (size_t)N_NODES * WPR;          // 16384*64 u64 = 8 MB
    float* alpha = (float*)(eadjP + (size_t)N_EDGES * WPR);
    float* beta  = alpha + 4096;
    float* gamma = beta + 4096;
    float* betaE = gamma + 4096;
    float* maxes = betaE + 16384;                       // 64 (padded)
    unsigned short* XtN = (unsigned short*)(maxes + 64);          // 128*4096 bf16
    unsigned short* XtE = XtN + (size_t)FN * N_NODES;             // 64*16384 bf16
    float* accN = (float*)(XtE + (size_t)FE * N_EDGES);           // NJS*4096*128
    float* zN   = accN + (size_t)NJS * N_NODES * FN;
    float* degN = zN + (size_t)NJS * N_NODES;
    float* accE = degN + (size_t)NJS * N_NODES;                   // EJS*4096*64
    float* zE   = accE + (size_t)EJS * N_NODES * FE;
    float* degE = zE + (size_t)EJS * N_NODES;

    k_pack<<<(N_NODES + N_EDGES) / 4, 256, 0, stream>>>(adj, eadj, adjP, eadjP);
    k_node_proj<<<N_NODES / 4, 256, 0, stream>>>(nf, Wn, pvn, pve, alpha, beta, gamma);
    k_edge_proj<<<N_EDGES / 4, 256, 0, stream>>>(ef, We, pve, betaE);
    k_maxes<<<2, 256, 0, stream>>>(beta, betaE, maxes);
    k_prep<<<dim3(N_NODES / 64, FN / 64), 256, 0, stream>>>(nf, XtN, N_NODES, FN);
    k_prep<<<dim3(N_EDGES / 64, FE / 64), 256, 0, stream>>>(ef, XtE, N_EDGES, FE);
    k_node_att<<<dim3(N_NODES / 32, NJS), 256, 0, stream>>>(XtN, adjP, alpha, beta, maxes, accN, zN, degN);
    k_edge_att<<<dim3(N_NODES / 64, EJS), 256, 0, stream>>>(XtE, eadjP, gamma, betaE, maxes, accE, zE, degE);
    k_node_out<<<N_NODES / 4, 256, 0, stream>>>(accN, zN, degN, Wn, out);
    k_edge_out<<<N_NODES / 4, 256, 0, stream>>>(accE, zE, degE, We, out);
}

// Round 5
// 210.542 us; speedup vs baseline: 1.0705x; 1.0705x over previous
//
#include <hip/hip_runtime.h>

typedef short bf16x8 __attribute__((ext_vector_type(8)));
typedef float f32x4 __attribute__((ext_vector_type(4)));
typedef unsigned long long u64;

#define N_NODES 4096
#define N_EDGES 16384
#define FN 128
#define FE 64
#define NJS 8
#define EJS 16
#define WPR 64   // packed u64 words per row (4096 bits)

#define PACK_BLOCKS ((N_NODES + N_EDGES) / 4)   // 5120
#define NPROJ_BLOCKS (N_NODES / 4)              // 1024
#define EPROJ_BLOCKS (N_EDGES / 4)              // 4096
#define PREPN_BLOCKS (N_NODES / 64)             // 64
#define PREPE_BLOCKS (N_EDGES / 64)             // 256
#define FRONT_BLOCKS (PACK_BLOCKS + NPROJ_BLOCKS + EPROJ_BLOCKS + PREPN_BLOCKS + PREPE_BLOCKS)

__device__ __forceinline__ float lrelu(float x) { return x >= 0.f ? x : 0.01f * x; }
// float -> bf16 round-to-nearest-even (finite inputs only)
__device__ __forceinline__ unsigned short f2bf(float f) {
    unsigned int x = __float_as_uint(f);
    return (unsigned short)((x + 0x7fffu + ((x >> 16) & 1u)) >> 16);
}

// ---- prep: src[j][f] f32 -> dst[j/8][F][8] bf16 (MFMA A-frag friendly) ----
__device__ __forceinline__ void prep_b(
    const float* __restrict__ src, unsigned short* __restrict__ dst,
    int j0, int F, int lf, float* tile /* [64][F+1] */) {
    const int t = threadIdx.x;
    const int P = F + 1;
    for (int it = 0; it < (F >> 4); ++it) {
        int idx = (it * 256 + t) * 4;
        int j = idx >> lf, f = idx & (F - 1);
        float4 v = *(const float4*)(src + (size_t)(j0 + j) * F + f);
        tile[j * P + f + 0] = v.x; tile[j * P + f + 1] = v.y;
        tile[j * P + f + 2] = v.z; tile[j * P + f + 3] = v.w;
    }
    __syncthreads();
    for (int it = 0; it < (F >> 5); ++it) {
        int c = it * 256 + t;
        int jo = c >> lf, f = c & (F - 1);
        bf16x8 v;
#pragma unroll
        for (int e = 0; e < 8; ++e) v[e] = (short)f2bf(tile[(jo * 8 + e) * P + f]);
        *(bf16x8*)(dst + (((size_t)(j0 >> 3) + jo) * F + f) * 8) = v;
    }
}

// ---- kernel 1 (fused front): pack masks + node/edge proj + prep, all independent ----
__global__ __launch_bounds__(256) void k_front(
    const float* __restrict__ nf, const float* __restrict__ ef,
    const int* __restrict__ adj, const int* __restrict__ eadj,
    const float* __restrict__ Wn, const float* __restrict__ We,
    const float* __restrict__ pvn, const float* __restrict__ pve,
    u64* __restrict__ adjP, u64* __restrict__ eadjP,
    float* __restrict__ alpha, float* __restrict__ beta, float* __restrict__ gamma,
    float* __restrict__ betaE,
    unsigned short* __restrict__ XbN, unsigned short* __restrict__ XbE) {
    __shared__ float smem[8256];   // 33 KB, union across branches
    int bx = blockIdx.x;
    const int wv = threadIdx.x >> 6, ln = threadIdx.x & 63;

    if (bx < PACK_BLOCKS) {
        // pack: word = (i>>8)*4 + (i&3), bit = (i>>2)&63  (verified R4 layout)
        const int row = bx * 4 + wv;
        const int* src;
        u64* dst;
        if (row < N_EDGES) {
            src = eadj + (size_t)row * N_NODES;
            dst = eadjP + (size_t)row * WPR;
        } else {
            src = adj + (size_t)(row - N_EDGES) * N_NODES;
            dst = adjP + (size_t)(row - N_EDGES) * WPR;
        }
#pragma unroll 4
        for (int chunk = 0; chunk < 16; ++chunk) {
            int4 v = *(const int4*)(src + chunk * 256 + ln * 4);
            u64 b0 = __ballot(v.x > 0);
            u64 b1 = __ballot(v.y > 0);
            u64 b2 = __ballot(v.z > 0);
            u64 b3 = __ballot(v.w > 0);
            if (ln < 4) dst[chunk * 4 + ln] = (ln == 0) ? b0 : (ln == 1) ? b1 : (ln == 2) ? b2 : b3;
        }
        return;
    }
    bx -= PACK_BLOCKS;
    if (bx < NPROJ_BLOCKS) {
        float* row = smem;   // [4][FN]
        const int i = bx * 4 + wv;
        float2 r2 = *(const float2*)(nf + (size_t)i * FN + ln * 2);
        row[wv * FN + ln * 2] = r2.x; row[wv * FN + ln * 2 + 1] = r2.y;
        __syncthreads();
        float h0 = 0.f, h1 = 0.f;
#pragma unroll 8
        for (int k = 0; k < FN; ++k) {
            float nv = row[wv * FN + k];
            float2 w2 = *(const float2*)(Wn + (size_t)k * FN + ln * 2);
            h0 = fmaf(nv, w2.x, h0); h1 = fmaf(nv, w2.y, h1);
        }
        float2 as = *(const float2*)(pvn + ln * 2);
        float2 an = *(const float2*)(pvn + FN + ln * 2);
        float2 bs = *(const float2*)(pve + ln * 2);
        float pa = h0 * as.x + h1 * as.y;
        float pb = h0 * an.x + h1 * an.y;
        float pg = h0 * bs.x + h1 * bs.y;
#pragma unroll
        for (int off = 32; off > 0; off >>= 1) {
            pa += __shfl_down(pa, off, 64);
            pb += __shfl_down(pb, off, 64);
            pg += __shfl_down(pg, off, 64);
        }
        if (ln == 0) { alpha[i] = pa; beta[i] = pb; gamma[i] = pg; }
        return;
    }
    bx -= NPROJ_BLOCKS;
    if (bx < EPROJ_BLOCKS) {
        float* row = smem;   // [4][FE]
        const int e = bx * 4 + wv;
        row[wv * FE + ln] = ef[(size_t)e * FE + ln];
        __syncthreads();
        float h = 0.f;
#pragma unroll 8
        for (int k = 0; k < FE; ++k)
            h = fmaf(row[wv * FE + k], We[(size_t)k * FE + ln], h);
        float p = h * pve[FN + ln];
#pragma unroll
        for (int off = 32; off > 0; off >>= 1) p += __shfl_down(p, off, 64);
        if (ln == 0) betaE[e] = p;
        return;
    }
    bx -= EPROJ_BLOCKS;
    if (bx < PREPN_BLOCKS) {
        prep_b(nf, XbN, bx * 64, FN, 7, smem);
        return;
    }
    bx -= PREPN_BLOCKS;
    prep_b(ef, XbE, bx * 64, FE, 6, smem);
}

// ---- kernel 2: global maxes of beta (block 0) and betaE (block 1), vectorized ----
__global__ __launch_bounds__(256) void k_maxes(
    const float* __restrict__ beta, const float* __restrict__ betaE,
    float* __restrict__ maxes) {
    const float* src = blockIdx.x == 0 ? beta : betaE;
    const int n = blockIdx.x == 0 ? N_NODES : N_EDGES;
    float m = -3.0e38f;
    for (int t = threadIdx.x * 4; t < n; t += 1024) {
        float4 v = *(const float4*)(src + t);
        m = fmaxf(m, fmaxf(fmaxf(v.x, v.y), fmaxf(v.z, v.w)));
    }
#pragma unroll
    for (int off = 32; off > 0; off >>= 1) m = fmaxf(m, __shfl_down(m, off, 64));
    __shared__ float sm[4];
    if ((threadIdx.x & 63) == 0) sm[threadIdx.x >> 6] = m;
    __syncthreads();
    if (threadIdx.x == 0)
        maxes[blockIdx.x] = fmaxf(fmaxf(sm[0], sm[1]), fmaxf(sm[2], sm[3]));
}

// ---- kernel 3: node attention, LDS-free barrier-free per-wave MFMA ----
// wave owns 16-i tile; A = Xb (global/L2), B = w generated in-register.
__global__ __launch_bounds__(256) void k_node_att(
    const unsigned short* __restrict__ Xb,   // [512][128][8] bf16
    const u64* __restrict__ adjP,
    const float* __restrict__ alpha, const float* __restrict__ beta,
    const float* __restrict__ maxes,
    float* __restrict__ accP, float* __restrict__ zP, float* __restrict__ degP) {
    const int t = threadIdx.x, l = t & 63, wid = t >> 6;
    const int l15 = l & 15, lq = l >> 4;
    const int bj = blockIdx.y;
    const int j0 = bj * (N_NODES / NJS);       // 512
    const int i0 = blockIdx.x * 64 + wid * 16;
    const int i = i0 + l15;
    const float a_i = alpha[i];
    const float m_i = lrelu(a_i + maxes[0]);
    const int wbase = (i0 >> 8) * 4 + (l15 & 3);
    const int mbit = (i >> 2) & 63;
    f32x4 acc[8] = {};
    float zacc = 0.f, dacc = 0.f;
    const u64* mp0 = adjP + (size_t)j0 * WPR + wbase + (size_t)(lq * 8) * WPR;
    const unsigned short* xb0 = Xb + (((size_t)(j0 >> 3) + lq) * FN + l15) * 8;
    const float* bb0 = beta + j0 + lq * 8;

    for (int ks = 0; ks < 16; ++ks) {
        const int jb = ks * 32;
        u64 mw[8];
        const u64* mp = mp0 + (size_t)jb * WPR;
#pragma unroll
        for (int e = 0; e < 8; ++e) mw[e] = mp[(size_t)e * WPR];
        float4 b0 = *(const float4*)(bb0 + jb);
        float4 b1 = *(const float4*)(bb0 + jb + 4);
        float bv[8] = {b0.x, b0.y, b0.z, b0.w, b1.x, b1.y, b1.z, b1.w};
        bf16x8 wf;
#pragma unroll
        for (int e = 0; e < 8; ++e) {
            int mk = (int)((mw[e] >> mbit) & 1);
            float s = lrelu(a_i + bv[e]);
            float w = mk ? __expf(s - m_i) : 0.f;
            zacc += w; dacc += (float)mk;
            wf[e] = (short)f2bf(w);
        }
        const unsigned short* xa = xb0 + (size_t)(jb >> 3) * (FN * 8);
#pragma unroll
        for (int mi = 0; mi < 8; ++mi) {
            bf16x8 a = *(const bf16x8*)(xa + mi * 128);
            acc[mi] = __builtin_amdgcn_mfma_f32_16x16x32_bf16(a, wf, acc[mi], 0, 0, 0);
        }
    }
    zacc += __shfl_xor(zacc, 16, 64); zacc += __shfl_xor(zacc, 32, 64);
    dacc += __shfl_xor(dacc, 16, 64); dacc += __shfl_xor(dacc, 32, 64);
    if (l < 16) {
        zP[bj * N_NODES + i] = zacc;
        degP[bj * N_NODES + i] = dacc;
    }
#pragma unroll
    for (int mi = 0; mi < 8; ++mi)
        *(f32x4*)(accP + ((size_t)bj * N_NODES + i) * FN + mi * 16 + lq * 4) = acc[mi];
}

// ---- kernel 4: edge attention, same structure (F=64, j-range 1024) ----
__global__ __launch_bounds__(256) void k_edge_att(
    const unsigned short* __restrict__ Xb,   // [2048][64][8] bf16
    const u64* __restrict__ eadjP,
    const float* __restrict__ gamma, const float* __restrict__ betaE,
    const float* __restrict__ maxes,
    float* __restrict__ accP, float* __restrict__ zP, float* __restrict__ degP) {
    const int t = threadIdx.x, l = t & 63, wid = t >> 6;
    const int l15 = l & 15, lq = l >> 4;
    const int bj = blockIdx.y;
    const int j0 = bj * (N_EDGES / EJS);       // 1024
    const int i0 = blockIdx.x * 64 + wid * 16;
    const int i = i0 + l15;
    const float a_i = gamma[i];
    const float m_i = lrelu(a_i + maxes[1]);
    const int wbase = (i0 >> 8) * 4 + (l15 & 3);
    const int mbit = (i >> 2) & 63;
    f32x4 acc[4] = {};
    float zacc = 0.f, dacc = 0.f;
    const u64* mp0 = eadjP + (size_t)j0 * WPR + wbase + (size_t)(lq * 8) * WPR;
    const unsigned short* xb0 = Xb + (((size_t)(j0 >> 3) + lq) * FE + l15) * 8;
    const float* bb0 = betaE + j0 + lq * 8;

    for (int ks = 0; ks < 32; ++ks) {
        const int jb = ks * 32;
        u64 mw[8];
        const u64* mp = mp0 + (size_t)jb * WPR;
#pragma unroll
        for (int e = 0; e < 8; ++e) mw[e] = mp[(size_t)e * WPR];
        float4 b0 = *(const float4*)(bb0 + jb);
        float4 b1 = *(const float4*)(bb0 + jb + 4);
        float bv[8] = {b0.x, b0.y, b0.z, b0.w, b1.x, b1.y, b1.z, b1.w};
        bf16x8 wf;
#pragma unroll
        for (int e = 0; e < 8; ++e) {
            int mk = (int)((mw[e] >> mbit) & 1);
            float s = lrelu(a_i + bv[e]);
            float w = mk ? __expf(s - m_i) : 0.f;
            zacc += w; dacc += (float)mk;
            wf[e] = (short)f2bf(w);
        }
        const unsigned short* xa = xb0 + (size_t)(jb >> 3) * (FE * 8);
#pragma unroll
        for (int mi = 0; mi < 4; ++mi) {
            bf16x8 a = *(const bf16x8*)(xa + mi * 128);
            acc[mi] = __builtin_amdgcn_mfma_f32_16x16x32_bf16(a, wf, acc[mi], 0, 0, 0);
        }
    }
    zacc += __shfl_xor(zacc, 16, 64); zacc += __shfl_xor(zacc, 32, 64);
    dacc += __shfl_xor(dacc, 16, 64); dacc += __shfl_xor(dacc, 32, 64);
    if (l < 16) {
        zP[bj * N_NODES + i] = zacc;
        degP[bj * N_NODES + i] = dacc;
    }
#pragma unroll
    for (int mi = 0; mi < 4; ++mi)
        *(f32x4*)(accP + ((size_t)bj * N_NODES + i) * FE + mi * 16 + lq * 4) = acc[mi];
}

// ---- kernel 5: node epilogue ----
__global__ __launch_bounds__(256) void k_node_out(
    const float* __restrict__ accP, const float* __restrict__ zP,
    const float* __restrict__ degP, const float* __restrict__ Wn,
    float* __restrict__ out) {
    __shared__ float ml[4][FN];
    const int wv = threadIdx.x >> 6, ln = threadIdx.x & 63;
    const int i = blockIdx.x * 4 + wv;
    float s0 = 0.f, s1 = 0.f;
#pragma unroll
    for (int js = 0; js < NJS; ++js) {
        float2 v = *(const float2*)(accP + ((size_t)js * N_NODES + i) * FN + ln * 2);
        s0 += v.x; s1 += v.y;
    }
    float z = 0.f, d = 0.f;
#pragma unroll
    for (int js = 0; js < NJS; ++js) { z += zP[js * N_NODES + i]; d += degP[js * N_NODES + i]; }
    float zd = z * d;
    float inv = zd > 0.f ? 1.f / zd : 0.f;
    ml[wv][ln * 2] = s0 * inv; ml[wv][ln * 2 + 1] = s1 * inv;
    __syncthreads();
    float o0 = 0.f, o1 = 0.f;
#pragma unroll 8
    for (int k = 0; k < FN; ++k) {
        float mvv = ml[wv][k];
        float2 w2 = *(const float2*)(Wn + (size_t)k * FN + ln * 2);
        o0 = fmaf(mvv, w2.x, o0); o1 = fmaf(mvv, w2.y, o1);
    }
    out[(size_t)i * 192 + ln * 2] = lrelu(o0);
    out[(size_t)i * 192 + ln * 2 + 1] = lrelu(o1);
}

// ---- kernel 6: edge epilogue ----
__global__ __launch_bounds__(256) void k_edge_out(
    const float* __restrict__ accP, const float* __restrict__ zP,
    const float* __restrict__ degP, const float* __restrict__ We,
    float* __restrict__ out) {
    __shared__ float ml[4][FE];
    const int wv = threadIdx.x >> 6, ln = threadIdx.x & 63;
    const int i = blockIdx.x * 4 + wv;
    float s = 0.f;
#pragma unroll
    for (int js = 0; js < EJS; ++js)
        s += accP[((size_t)js * N_NODES + i) * FE + ln];
    float z = 0.f, d = 0.f;
#pragma unroll
    for (int js = 0; js < EJS; ++js) { z += zP[js * N_NODES + i]; d += degP[js * N_NODES + i]; }
    float zd = z * d;
    float inv = zd > 0.f ? 1.f / zd : 0.f;
    ml[wv][ln] = s * inv;
    __syncthreads();
    float o = 0.f;
#pragma unroll 8
    for (int k = 0; k < FE; ++k)
        o = fmaf(ml[wv][k], We[(size_t)k * FE + ln], o);
    out[(size_t)i * 192 + 128 + ln] = lrelu(o);
}

extern "C" void kernel_launch(void* const* d_in, const int* in_sizes, int n_in,
                              void* d_out, int out_size, void* d_ws, size_t ws_size,
                              hipStream_t stream) {
    (void)in_sizes; (void)n_in; (void)out_size; (void)ws_size;
    const float* nf   = (const float*)d_in[0];
    const float* ef   = (const float*)d_in[1];
    const int*   adj  = (const int*)d_in[2];
    const int*   eadj = (const int*)d_in[3];
    const float* Wn   = (const float*)d_in[4];
    const float* We   = (const float*)d_in[5];
    const float* pvn  = (const float*)d_in[6];
    const float* pve  = (const float*)d_in[7];
    float* out = (float*)d_out;

    u64* adjP  = (u64*)d_ws;                            // 2 MB
    u64* eadjP = adjP + (size_t)N_NODES * WPR;          // 8 MB
    float* alpha = (float*)(eadjP + (size_t)N_EDGES * WPR);
    float* beta  = alpha + 4096;
    float* gamma = beta + 4096;
    float* betaE = gamma + 4096;
    float* maxes = betaE + 16384;                       // 64 (padded)
    unsigned short* XbN = (unsigned short*)(maxes + 64);          // 512*128*8 bf16 = 1 MB
    unsigned short* XbE = XbN + (size_t)(N_NODES / 8) * FN * 8;   // 2048*64*8 bf16 = 2 MB
    float* accN = (float*)(XbE + (size_t)(N_EDGES / 8) * FE * 8); // 16.8 MB
    float* zN   = accN + (size_t)NJS * N_NODES * FN;
    float* degN = zN + (size_t)NJS * N_NODES;
    float* accE = degN + (size_t)NJS * N_NODES;                   // 16.8 MB
    float* zE   = accE + (size_t)EJS * N_NODES * FE;
    float* degE = zE + (size_t)EJS * N_NODES;

    k_front<<<FRONT_BLOCKS, 256, 0, stream>>>(nf, ef, adj, eadj, Wn, We, pvn, pve,
                                              adjP, eadjP, alpha, beta, gamma, betaE, XbN, XbE);
    k_maxes<<<2, 256, 0, stream>>>(beta, betaE, maxes);
    k_node_att<<<dim3(N_NODES / 64, NJS), 256, 0, stream>>>(XbN, adjP, alpha, beta, maxes, accN, zN, degN);
    k_edge_att<<<dim3(N_NODES / 64, EJS), 256, 0, stream>>>(XbE, eadjP, gamma, betaE, maxes, accE, zE, degE);
    k_node_out<<<N_NODES / 4, 256, 0, stream>>>(accN, zN, degN, Wn, out);
    k_edge_out<<<N_NODES / 4, 256, 0, stream>>>(accE, zE, degE, We, out);
}